// Round 2
// baseline (1278.579 us; speedup 1.0000x reference)
//
#include <hip/hip_runtime.h>
#include <hip/hip_bf16.h>

#define L2E 1.4426950408889634f

// ---------------- GEMM: C[M,N] = A[M,K] @ B[N,K]^T (fp32) ----------------
__global__ __launch_bounds__(256) void gemm_abt(
    const float* __restrict__ A, const float* __restrict__ B,
    float* __restrict__ C, int M, int N, int K) {
  __shared__ __align__(16) float As[16][64];
  __shared__ __align__(16) float Bs[16][64];
  const int t = threadIdx.x;
  const int row0 = blockIdx.y * 64, col0 = blockIdx.x * 64;
  const int ty = t >> 4, tx = t & 15;
  const int lr = t >> 2, lk = (t & 3) * 4;
  float acc[4][4] = {};
  for (int k0 = 0; k0 < K; k0 += 16) {
    float4 av = *(const float4*)(A + (size_t)(row0 + lr) * K + k0 + lk);
    float4 bv = *(const float4*)(B + (size_t)(col0 + lr) * K + k0 + lk);
    __syncthreads();
    As[lk + 0][lr] = av.x; As[lk + 1][lr] = av.y;
    As[lk + 2][lr] = av.z; As[lk + 3][lr] = av.w;
    Bs[lk + 0][lr] = bv.x; Bs[lk + 1][lr] = bv.y;
    Bs[lk + 2][lr] = bv.z; Bs[lk + 3][lr] = bv.w;
    __syncthreads();
#pragma unroll
    for (int kk = 0; kk < 16; ++kk) {
      float4 a4 = *(const float4*)&As[kk][ty * 4];
      float4 b4 = *(const float4*)&Bs[kk][tx * 4];
      const float aa[4] = {a4.x, a4.y, a4.z, a4.w};
      const float bb[4] = {b4.x, b4.y, b4.z, b4.w};
#pragma unroll
      for (int i = 0; i < 4; ++i)
#pragma unroll
        for (int j = 0; j < 4; ++j)
          acc[i][j] = fmaf(aa[i], bb[j], acc[i][j]);
    }
  }
#pragma unroll
  for (int i = 0; i < 4; ++i) {
    float4 o = make_float4(acc[i][0], acc[i][1], acc[i][2], acc[i][3]);
    *(float4*)(C + (size_t)(row0 + ty * 4 + i) * N + col0 + tx * 4) = o;
  }
}

// ------------- et/es: out[r*8+h] = sum_d X[r,h*32+d] * a[h,aoff+d] -------------
__global__ __launch_bounds__(256) void escore_kernel(
    const float* __restrict__ X, const float* __restrict__ a,
    int aoff, int rows, float* __restrict__ out) {
  int t = blockIdx.x * 256 + threadIdx.x;
  if (t >= rows * 8) return;
  int r = t >> 3, h = t & 7;
  const float* xp = X + (size_t)r * 256 + h * 32;
  const float* ap = a + h * 64 + aoff;
  float s = 0.f;
#pragma unroll
  for (int d = 0; d < 32; d += 4) {
    float4 xv = *(const float4*)(xp + d);
    float4 av = *(const float4*)(ap + d);
    s = fmaf(xv.x, av.x, s); s = fmaf(xv.y, av.y, s);
    s = fmaf(xv.z, av.z, s); s = fmaf(xv.w, av.w, s);
  }
  out[t] = s;
}

// ------------- pass1: per-(row,head) masked online max & sumexp (exp2 domain) -------------
// c-side blocks [0,128): rows of c (4096), sources d (2048), adj[n*2048+m]
// d-side blocks [128,192): rows of d (2048), sources c (4096), adj[m*2048+n] (transposed)
__global__ __launch_bounds__(256) void attn_pass1(
    const float* __restrict__ et_c, const float* __restrict__ es_c,
    const float* __restrict__ et_d, const float* __restrict__ es_d,
    const int* __restrict__ adj,
    float* __restrict__ mx_c, float* __restrict__ sm_c,
    float* __restrict__ mx_d, float* __restrict__ sm_d) {
  __shared__ float es_s[512];
  __shared__ int adj_s[32][65];
  const int b = blockIdx.x;
  const bool cs = b < 128;
  const int r0 = (cs ? b : b - 128) * 32;
  const float* et = cs ? et_c : et_d;
  const float* es = cs ? es_c : es_d;
  float* mxo = cs ? mx_c : mx_d;
  float* smo = cs ? sm_c : sm_d;
  const int M = cs ? 2048 : 4096;
  const int t = threadIdx.x;
  const int r = t >> 3, h = t & 7;
  const float myet = et[(size_t)(r0 + r) * 8 + h];
  float mx2 = -1e30f, sum = 0.f;
  for (int m0 = 0; m0 < M; m0 += 64) {
    __syncthreads();
    es_s[t] = es[m0 * 8 + t];
    es_s[t + 256] = es[m0 * 8 + t + 256];
    if (cs) {
#pragma unroll
      for (int idx = t; idx < 512; idx += 256) {
        int rr = idx >> 4, c4 = idx & 15;
        int4 v = *(const int4*)(adj + (size_t)(r0 + rr) * 2048 + m0 + c4 * 4);
        adj_s[rr][c4 * 4 + 0] = v.x; adj_s[rr][c4 * 4 + 1] = v.y;
        adj_s[rr][c4 * 4 + 2] = v.z; adj_s[rr][c4 * 4 + 3] = v.w;
      }
    } else {
#pragma unroll
      for (int idx = t; idx < 2048; idx += 256) {
        int jj = idx >> 5, rr = idx & 31;
        adj_s[rr][jj] = adj[(size_t)(m0 + jj) * 2048 + r0 + rr];
      }
    }
    __syncthreads();
#pragma unroll 8
    for (int j = 0; j < 64; ++j) {
      float t1 = myet + es_s[j * 8 + h];
      float e2 = fmaxf(t1, 0.2f * t1) * L2E;   // LeakyReLU, exp2 domain
      float cand = adj_s[r][j] > 0 ? e2 : -2e30f;
      float nm = fmaxf(mx2, cand);
      sum = sum * exp2f(mx2 - nm) + exp2f(cand - nm);
      mx2 = nm;
    }
  }
  mxo[(size_t)(r0 + r) * 8 + h] = mx2;
  smo[(size_t)(r0 + r) * 8 + h] = sum;
}

// ------------- pass2: weighted PV accumulate + BN + ReLU + fp32 store -------------
// block = 16 rows x 8 heads x 2 half-D; m-tiles of 32 staged in LDS (head stride 36)
__global__ __launch_bounds__(256) void attn_pass2(
    const float* __restrict__ S_c, const float* __restrict__ et_c,
    const float* __restrict__ es_c, const float* __restrict__ mx_c,
    const float* __restrict__ sm_c,
    const float* __restrict__ S_d, const float* __restrict__ et_d,
    const float* __restrict__ es_d, const float* __restrict__ mx_d,
    const float* __restrict__ sm_d,
    const int* __restrict__ adj,
    const float* __restrict__ gc, const float* __restrict__ bc,
    const float* __restrict__ gd, const float* __restrict__ bd,
    float* __restrict__ out) {
  __shared__ __align__(16) float S_s[32 * 288];   // [j][h*36 + d], 36.9KB
  __shared__ float es_s[256];
  __shared__ int adj_s[16 * 33];
  const int b = blockIdx.x;
  const bool cs = b < 256;
  const int r0 = (cs ? b : b - 256) * 16;
  const float* S  = cs ? S_c : S_d;
  const float* et = cs ? et_c : et_d;
  const float* es = cs ? es_c : es_d;
  const float* mx = cs ? mx_c : mx_d;
  const float* sm = cs ? sm_c : sm_d;
  const float* g  = cs ? gc : gd;
  const float* be = cs ? bc : bd;
  float* outp = cs ? out : out + (size_t)4096 * 256;
  const int M = cs ? 2048 : 4096;
  const int t = threadIdx.x;
  const int r = t >> 4, h = (t >> 1) & 7, dh = t & 1;
  const size_t rowi = (size_t)(r0 + r) * 8 + h;
  const float myet = et[rowi];
  const float mx2 = mx[rowi];
  const float rs = 1.f / fmaxf(sm[rowi], 1e-30f);
  float acc[16] = {};
  for (int m0 = 0; m0 < M; m0 += 32) {
    __syncthreads();
#pragma unroll
    for (int idx = t; idx < 2048; idx += 256) {   // 32 rows * 64 float4
      int j = idx >> 6, q = idx & 63;
      float4 v = *(const float4*)(S + (size_t)(m0 + j) * 256 + q * 4);
      float* dst = &S_s[j * 288 + (q >> 3) * 36 + (q & 7) * 4];
      dst[0] = v.x; dst[1] = v.y; dst[2] = v.z; dst[3] = v.w;
    }
    es_s[t] = es[m0 * 8 + t];
    if (cs) {
      if (t < 128) {
        int rr = t >> 3, c4 = t & 7;
        int4 v = *(const int4*)(adj + (size_t)(r0 + rr) * 2048 + m0 + c4 * 4);
        int* dst = &adj_s[rr * 33 + c4 * 4];
        dst[0] = v.x; dst[1] = v.y; dst[2] = v.z; dst[3] = v.w;
      }
    } else {
#pragma unroll
      for (int idx = t; idx < 512; idx += 256) {
        int jj = idx >> 4, rr = idx & 15;
        adj_s[rr * 33 + jj] = adj[(size_t)(m0 + jj) * 2048 + r0 + rr];
      }
    }
    __syncthreads();
#pragma unroll 4
    for (int j = 0; j < 32; ++j) {
      float t1 = myet + es_s[j * 8 + h];
      float e2 = fmaxf(t1, 0.2f * t1) * L2E;
      float pe = exp2f(e2 - mx2);
      float p = adj_s[r * 33 + j] > 0 ? pe : 0.f;
      const float* sp = &S_s[j * 288 + h * 36 + dh * 16];
#pragma unroll
      for (int i = 0; i < 4; ++i) {
        float4 v = *(const float4*)(sp + i * 4);
        acc[i * 4 + 0] = fmaf(p, v.x, acc[i * 4 + 0]);
        acc[i * 4 + 1] = fmaf(p, v.y, acc[i * 4 + 1]);
        acc[i * 4 + 2] = fmaf(p, v.z, acc[i * 4 + 2]);
        acc[i * 4 + 3] = fmaf(p, v.w, acc[i * 4 + 3]);
      }
    }
  }
  const int cb = h * 32 + dh * 16;
  const float bnf = 0.99999500003749969f;   // 1/sqrt(1+1e-5)
  float* op = outp + (size_t)(r0 + r) * 256 + cb;
#pragma unroll
  for (int i = 0; i < 4; ++i) {
    float4 o;
    o.x = fmaxf(fmaf(acc[i * 4 + 0] * rs, g[cb + i * 4 + 0] * bnf, be[cb + i * 4 + 0]), 0.f);
    o.y = fmaxf(fmaf(acc[i * 4 + 1] * rs, g[cb + i * 4 + 1] * bnf, be[cb + i * 4 + 1]), 0.f);
    o.z = fmaxf(fmaf(acc[i * 4 + 2] * rs, g[cb + i * 4 + 2] * bnf, be[cb + i * 4 + 2]), 0.f);
    o.w = fmaxf(fmaf(acc[i * 4 + 3] * rs, g[cb + i * 4 + 3] * bnf, be[cb + i * 4 + 3]), 0.f);
    *(float4*)(op + i * 4) = o;
  }
}

extern "C" void kernel_launch(void* const* d_in, const int* in_sizes, int n_in,
                              void* d_out, int out_size, void* d_ws, size_t ws_size,
                              hipStream_t stream) {
  const float* c_feat = (const float*)d_in[0];   // [4096,256]
  const float* d_feat = (const float*)d_in[1];   // [2048,256]
  const int*   adj    = (const int*)d_in[2];     // [4096,2048]
  const float* c_W    = (const float*)d_in[3];   // [256,256]
  const float* c_a    = (const float*)d_in[4];   // [8,64]
  const float* d_W    = (const float*)d_in[5];
  const float* d_a    = (const float*)d_in[6];
  const float* c_bn_g = (const float*)d_in[7];
  const float* c_bn_b = (const float*)d_in[8];
  const float* d_bn_g = (const float*)d_in[9];
  const float* d_bn_b = (const float*)d_in[10];
  float* out = (float*)d_out;

  float* ws = (float*)d_ws;                      // ~12.8 MB used
  float* S_c  = ws;                    // 2048*256  (d_feat @ c_W^T)
  float* T_c  = S_c + 2048 * 256;      // 4096*256  (c_feat @ c_W^T)
  float* S_d  = T_c + 4096 * 256;      // 4096*256  (c_feat @ d_W^T)
  float* T_d  = S_d + 4096 * 256;      // 2048*256  (d_feat @ d_W^T)
  float* et_c = T_d + 2048 * 256;      // 4096*8
  float* es_c = et_c + 4096 * 8;       // 2048*8
  float* et_d = es_c + 2048 * 8;       // 2048*8
  float* es_d = et_d + 2048 * 8;       // 4096*8
  float* mx_c = es_d + 4096 * 8;       // 4096*8
  float* sm_c = mx_c + 4096 * 8;       // 4096*8
  float* mx_d = sm_c + 4096 * 8;       // 2048*8
  float* sm_d = mx_d + 2048 * 8;       // 2048*8

  dim3 blk(256);
  gemm_abt<<<dim3(4, 32), blk, 0, stream>>>(d_feat, c_W, S_c, 2048, 256, 256);
  gemm_abt<<<dim3(4, 64), blk, 0, stream>>>(c_feat, c_W, T_c, 4096, 256, 256);
  gemm_abt<<<dim3(4, 64), blk, 0, stream>>>(c_feat, d_W, S_d, 4096, 256, 256);
  gemm_abt<<<dim3(4, 32), blk, 0, stream>>>(d_feat, d_W, T_d, 2048, 256, 256);

  escore_kernel<<<128, blk, 0, stream>>>(T_c, c_a, 0, 4096, et_c);
  escore_kernel<<<64,  blk, 0, stream>>>(S_c, c_a, 32, 2048, es_c);
  escore_kernel<<<64,  blk, 0, stream>>>(T_d, d_a, 0, 2048, et_d);
  escore_kernel<<<128, blk, 0, stream>>>(S_d, d_a, 32, 4096, es_d);

  attn_pass1<<<192, blk, 0, stream>>>(et_c, es_c, et_d, es_d, adj,
                                      mx_c, sm_c, mx_d, sm_d);

  attn_pass2<<<384, blk, 0, stream>>>(S_c, et_c, es_c, mx_c, sm_c,
                                      S_d, et_d, es_d, mx_d, sm_d,
                                      adj, c_bn_g, c_bn_b, d_bn_g, d_bn_b, out);
}

// Round 3
// 186.114 us; speedup vs baseline: 6.8699x; 6.8699x over previous
//
#include <hip/hip_runtime.h>
#include <hip/hip_bf16.h>

#define L2E 1.4426950408889634f
#define BNF 0.99999500003749969f   // 1/sqrt(1+1e-5)

typedef __attribute__((ext_vector_type(4))) float f4;
typedef __attribute__((ext_vector_type(4))) float f32x4;
typedef __attribute__((ext_vector_type(8))) short bfrag;   // 8 bf16 = 4 VGPRs

__device__ __forceinline__ int cvtpk(float lo, float hi) {
  int r;
  asm("v_cvt_pk_bf16_f32 %0, %1, %2" : "=v"(r) : "v"(lo), "v"(hi));
  return r;
}

// ---------------- GEMM: C[M,N] = A[M,K] @ B[N,K]^T (fp32) ----------------
__global__ __launch_bounds__(256) void gemm_abt(
    const float* __restrict__ A, const float* __restrict__ B,
    float* __restrict__ C, int M, int N, int K) {
  __shared__ __align__(16) float As[16][64];
  __shared__ __align__(16) float Bs[16][64];
  const int t = threadIdx.x;
  const int row0 = blockIdx.y * 64, col0 = blockIdx.x * 64;
  const int ty = t >> 4, tx = t & 15;
  const int lr = t >> 2, lk = (t & 3) * 4;
  float acc[4][4] = {};
  for (int k0 = 0; k0 < K; k0 += 16) {
    float4 av = *(const float4*)(A + (size_t)(row0 + lr) * K + k0 + lk);
    float4 bv = *(const float4*)(B + (size_t)(col0 + lr) * K + k0 + lk);
    __syncthreads();
    As[lk + 0][lr] = av.x; As[lk + 1][lr] = av.y;
    As[lk + 2][lr] = av.z; As[lk + 3][lr] = av.w;
    Bs[lk + 0][lr] = bv.x; Bs[lk + 1][lr] = bv.y;
    Bs[lk + 2][lr] = bv.z; Bs[lk + 3][lr] = bv.w;
    __syncthreads();
#pragma unroll
    for (int kk = 0; kk < 16; ++kk) {
      float4 a4 = *(const float4*)&As[kk][ty * 4];
      float4 b4 = *(const float4*)&Bs[kk][tx * 4];
      const float aa[4] = {a4.x, a4.y, a4.z, a4.w};
      const float bb[4] = {b4.x, b4.y, b4.z, b4.w};
#pragma unroll
      for (int i = 0; i < 4; ++i)
#pragma unroll
        for (int j = 0; j < 4; ++j)
          acc[i][j] = fmaf(aa[i], bb[j], acc[i][j]);
    }
  }
#pragma unroll
  for (int i = 0; i < 4; ++i) {
    float4 o = make_float4(acc[i][0], acc[i][1], acc[i][2], acc[i][3]);
    *(float4*)(C + (size_t)(row0 + ty * 4 + i) * N + col0 + tx * 4) = o;
  }
}

// ------- wa[h][k] = L2E * sum_{d<32} a[h*64+d] * W[(h*32+d)*256 + k] -------
__global__ __launch_bounds__(256) void wa_kernel(
    const float* __restrict__ W, const float* __restrict__ a,
    float* __restrict__ wa) {
  int idx = blockIdx.x * 256 + threadIdx.x;   // 2048
  int h = idx >> 8, k = idx & 255;
  float s = 0.f;
#pragma unroll 8
  for (int d = 0; d < 32; ++d)
    s = fmaf(a[h * 64 + d], W[(size_t)(h * 32 + d) * 256 + k], s);
  wa[idx] = s * L2E;
}

// ------- et2[r][h] = sum_k X[r][k] * wa[h][k]  (wa pre-scaled by L2E) -------
__global__ __launch_bounds__(256) void et_kernel(
    const float* __restrict__ X, const float* __restrict__ wa,
    float* __restrict__ et2, int rows) {
  int idx = blockIdx.x * 256 + threadIdx.x;
  if (idx >= rows * 8) return;
  int r = idx >> 3, h = idx & 7;
  const float* xp = X + (size_t)r * 256;
  const float* ap = wa + h * 256;
  float s = 0.f;
#pragma unroll 16
  for (int k = 0; k < 256; k += 4) {
    f4 xv = *(const f4*)(xp + k);
    f4 av = *(const f4*)(ap + k);
    s = fmaf(xv.x, av.x, s); s = fmaf(xv.y, av.y, s);
    s = fmaf(xv.z, av.z, s); s = fmaf(xv.w, av.w, s);
  }
  et2[idx] = s;
}

// ------- es2t[h][m] = L2E * sum_{d<32} S[m][h*32+d] * a[h*64+32+d] -------
__global__ __launch_bounds__(256) void escore_t(
    const float* __restrict__ S, const float* __restrict__ a,
    float* __restrict__ es2t, int M, int Ml2) {
  int idx = blockIdx.x * 256 + threadIdx.x;
  int h = idx >> Ml2, m = idx & (M - 1);
  const float* sp = S + (size_t)m * 256 + h * 32;
  const float* ap = a + h * 64 + 32;
  float s = 0.f;
#pragma unroll
  for (int d = 0; d < 32; d += 4) {
    f4 xv = *(const f4*)(sp + d);
    f4 av = *(const f4*)(ap + d);
    s = fmaf(xv.x, av.x, s); s = fmaf(xv.y, av.y, s);
    s = fmaf(xv.z, av.z, s); s = fmaf(xv.w, av.w, s);
  }
  es2t[(size_t)h * M + m] = s * L2E;
}

// ------- pack adjacency into bitmasks: adjP[n][m/32], adjPT[m][n/32] -------
__global__ __launch_bounds__(256) void pack_adj(
    const int* __restrict__ adj, unsigned* __restrict__ adjP,
    unsigned* __restrict__ adjPT) {
  __shared__ int s[64][65];
  const int n0 = blockIdx.y * 64, m0 = blockIdx.x * 64;
  const int t = threadIdx.x;
#pragma unroll
  for (int i = 0; i < 4; ++i) {
    int idx = t + i * 256;
    int r = idx >> 4, c4 = (idx & 15) * 4;
    int4 v = *(const int4*)(adj + (size_t)(n0 + r) * 2048 + m0 + c4);
    s[r][c4 + 0] = v.x; s[r][c4 + 1] = v.y;
    s[r][c4 + 2] = v.z; s[r][c4 + 3] = v.w;
  }
  __syncthreads();
  const int w = t >> 6, l = t & 63;
#pragma unroll 4
  for (int rr = 0; rr < 16; ++rr) {
    int r = w * 16 + rr;
    unsigned long long b = __ballot(s[r][l] != 0);
    if (l == 0) {
      adjP[(size_t)(n0 + r) * 64 + (m0 >> 5)] = (unsigned)b;
      adjP[(size_t)(n0 + r) * 64 + (m0 >> 5) + 1] = (unsigned)(b >> 32);
    }
  }
#pragma unroll 4
  for (int cc = 0; cc < 16; ++cc) {
    int m = m0 + w * 16 + cc;
    unsigned long long b = __ballot(s[l][w * 16 + cc] != 0);
    if (l == 0) {
      adjPT[(size_t)m * 128 + (n0 >> 5)] = (unsigned)b;
      adjPT[(size_t)m * 128 + (n0 >> 5) + 1] = (unsigned)(b >> 32);
    }
  }
}

// ------- S[M][256] fp32 -> Sbt[256][M] bf16 (transposed, RNE) -------
__global__ __launch_bounds__(256) void sconvert(
    const float* __restrict__ S, unsigned short* __restrict__ Sbt, int M) {
  __shared__ float s[64][65];
  const int m0 = blockIdx.x * 64, c0 = blockIdx.y * 64;
  const int t = threadIdx.x;
#pragma unroll
  for (int i = 0; i < 4; ++i) {
    int idx = t + i * 256;
    int r = idx >> 4, c4 = (idx & 15) * 4;
    f4 v = *(const f4*)(S + (size_t)(m0 + r) * 256 + c0 + c4);
    s[r][c4 + 0] = v.x; s[r][c4 + 1] = v.y;
    s[r][c4 + 2] = v.z; s[r][c4 + 3] = v.w;
  }
  __syncthreads();
  const int cc = t >> 2, mi = (t & 3) * 16;
  unsigned tmp[8];
#pragma unroll
  for (int j = 0; j < 8; ++j)
    tmp[j] = (unsigned)cvtpk(s[mi + 2 * j][cc], s[mi + 2 * j + 1][cc]);
  uint4* dst = (uint4*)(Sbt + (size_t)(c0 + cc) * M + m0 + mi);
  dst[0] = make_uint4(tmp[0], tmp[1], tmp[2], tmp[3]);
  dst[1] = make_uint4(tmp[4], tmp[5], tmp[6], tmp[7]);
}

// ------- fused attention: P-gen (exp2, masked) -> MFMA PV + MFMA den -------
__device__ __forceinline__ bfrag make_pfrag(float et, const float* es,
                                            unsigned bits) {
  f4 e0 = *(const f4*)es;
  f4 e1 = *(const f4*)(es + 4);
  float xv[8] = {e0.x, e0.y, e0.z, e0.w, e1.x, e1.y, e1.z, e1.w};
  float p[8];
#pragma unroll
  for (int e = 0; e < 8; ++e) {
    float x = et + xv[e];
    x = fmaxf(x, 0.2f * x);                 // LeakyReLU (exp2 domain)
    float pe = __builtin_amdgcn_exp2f(x);
    p[e] = ((bits >> e) & 1u) ? pe : 0.f;
  }
  union { bfrag v; int i[4]; } u;
#pragma unroll
  for (int e = 0; e < 4; ++e) u.i[e] = cvtpk(p[2 * e], p[2 * e + 1]);
  return u.v;
}

template <int FINAL>
__global__ __launch_bounds__(256) void fused_attn(
    const float* __restrict__ et2,          // [rows][8], pre-scaled L2E
    const float* __restrict__ es2t,         // [8][M], pre-scaled L2E
    const unsigned* __restrict__ adjPk,     // [rows][M/32]
    const unsigned short* __restrict__ Sbt, // [256][M] bf16
    float* __restrict__ pnum,               // [cc][rows][256]
    float* __restrict__ pden,               // [cc][rows][8]
    float* __restrict__ outp,               // [rows][256] (FINAL)
    const float* __restrict__ bng, const float* __restrict__ bnb,
    int M, int CH) {
  const int n0 = blockIdx.x * 16;
  const int chunk = blockIdx.y;
  const int ROWS = gridDim.x * 16;
  const int mstart = chunk * CH, mend = mstart + CH;
  const int Mw = M >> 5;
  const int tid = threadIdx.x;
  const int w = tid >> 6, l = tid & 63;
  const int g = l >> 4, c16 = l & 15;
  const int hA = w * 2, hB = w * 2 + 1;
  const int row = n0 + c16;
  const float etA = et2[row * 8 + hA];
  const float etB = et2[row * 8 + hB];
  const unsigned* adjrow = adjPk + (size_t)row * Mw;
  const float* esArow = es2t + (size_t)hA * M;
  const float* esBrow = es2t + (size_t)hB * M;
  const unsigned short* SbtA0 = Sbt + (size_t)(hA * 32 + c16) * M;
  const unsigned short* SbtA1 = Sbt + (size_t)(hA * 32 + 16 + c16) * M;
  const unsigned short* SbtB0 = Sbt + (size_t)(hB * 32 + c16) * M;
  const unsigned short* SbtB1 = Sbt + (size_t)(hB * 32 + 16 + c16) * M;
  f32x4 accA0 = {0.f, 0.f, 0.f, 0.f}, accA1 = accA0, denA = accA0;
  f32x4 accB0 = accA0, accB1 = accA0, denB = accA0;
  union { bfrag v; int i[4]; } uo;
#pragma unroll
  for (int e = 0; e < 4; ++e) uo.i[e] = 0x3F803F80;   // bf16(1.0) pairs
  const bfrag ones = uo.v;

  for (int m0 = mstart; m0 < mend; m0 += 32) {
    const unsigned bits = (adjrow[m0 >> 5] >> (g * 8)) & 0xffu;
    const int mo = m0 + g * 8;
    bfrag aA = make_pfrag(etA, esArow + mo, bits);
    bfrag aB = make_pfrag(etB, esBrow + mo, bits);
    bfrag bA0 = *(const bfrag*)(SbtA0 + mo);
    bfrag bA1 = *(const bfrag*)(SbtA1 + mo);
    bfrag bB0 = *(const bfrag*)(SbtB0 + mo);
    bfrag bB1 = *(const bfrag*)(SbtB1 + mo);
    accA0 = __builtin_amdgcn_mfma_f32_16x16x32_bf16(aA, bA0, accA0, 0, 0, 0);
    accA1 = __builtin_amdgcn_mfma_f32_16x16x32_bf16(aA, bA1, accA1, 0, 0, 0);
    denA  = __builtin_amdgcn_mfma_f32_16x16x32_bf16(aA, ones, denA, 0, 0, 0);
    accB0 = __builtin_amdgcn_mfma_f32_16x16x32_bf16(aB, bB0, accB0, 0, 0, 0);
    accB1 = __builtin_amdgcn_mfma_f32_16x16x32_bf16(aB, bB1, accB1, 0, 0, 0);
    denB  = __builtin_amdgcn_mfma_f32_16x16x32_bf16(aB, ones, denB, 0, 0, 0);
  }

  // C/D layout: col = c16, row = g*4 + reg  (verified m89)
#define EPILOGUE(acc0, acc1, den, h)                                          \
  {                                                                           \
    const int c0 = (h) * 32 + c16, c1 = (h) * 32 + 16 + c16;                  \
    if (FINAL) {                                                              \
      const float g0 = bng[c0] * BNF, b0 = bnb[c0];                           \
      const float g1 = bng[c1] * BNF, b1 = bnb[c1];                           \
      _Pragma("unroll") for (int i = 0; i < 4; ++i) {                         \
        float rs = 1.f / fmaxf(den[i], 1e-30f);                               \
        float* op = outp + (size_t)(n0 + g * 4 + i) * 256;                    \
        op[c0] = fmaxf(fmaf(acc0[i] * rs, g0, b0), 0.f);                      \
        op[c1] = fmaxf(fmaf(acc1[i] * rs, g1, b1), 0.f);                      \
      }                                                                       \
    } else {                                                                  \
      _Pragma("unroll") for (int i = 0; i < 4; ++i) {                         \
        size_t rr = (size_t)chunk * ROWS + n0 + g * 4 + i;                    \
        pnum[rr * 256 + c0] = acc0[i];                                        \
        pnum[rr * 256 + c1] = acc1[i];                                        \
        if (c16 == 0) pden[rr * 8 + (h)] = den[i];                            \
      }                                                                       \
    }                                                                         \
  }
  EPILOGUE(accA0, accA1, denA, hA)
  EPILOGUE(accB0, accB1, denB, hB)
#undef EPILOGUE
}

// ------- finalize (chunked): sum partials, divide, BN, ReLU -------
__global__ __launch_bounds__(256) void finalize_k(
    const float* __restrict__ pnum, const float* __restrict__ pden,
    float* __restrict__ outp, const float* __restrict__ bng,
    const float* __restrict__ bnb, int rows, int cc) {
  int idx = blockIdx.x * 256 + threadIdx.x;   // rows*64, 4 cols each
  int r = idx >> 6, c4 = (idx & 63) * 4;
  int h = c4 >> 5;
  f4 num = {0.f, 0.f, 0.f, 0.f};
  float den = 0.f;
  for (int c = 0; c < cc; ++c) {
    size_t rr = (size_t)c * rows + r;
    num += *(const f4*)(pnum + rr * 256 + c4);
    den += pden[rr * 8 + h];
  }
  float rs = 1.f / fmaxf(den, 1e-30f);
  f4 gm = *(const f4*)(bng + c4);
  f4 bb = *(const f4*)(bnb + c4);
  f4 o;
  o.x = fmaxf(fmaf(num.x * rs, gm.x * BNF, bb.x), 0.f);
  o.y = fmaxf(fmaf(num.y * rs, gm.y * BNF, bb.y), 0.f);
  o.z = fmaxf(fmaf(num.z * rs, gm.z * BNF, bb.z), 0.f);
  o.w = fmaxf(fmaf(num.w * rs, gm.w * BNF, bb.w), 0.f);
  *(f4*)(outp + (size_t)r * 256 + c4) = o;
}

extern "C" void kernel_launch(void* const* d_in, const int* in_sizes, int n_in,
                              void* d_out, int out_size, void* d_ws, size_t ws_size,
                              hipStream_t stream) {
  const float* c_feat = (const float*)d_in[0];   // [4096,256]
  const float* d_feat = (const float*)d_in[1];   // [2048,256]
  const int*   adj    = (const int*)d_in[2];     // [4096,2048]
  const float* c_W    = (const float*)d_in[3];
  const float* c_a    = (const float*)d_in[4];   // [8,64]
  const float* d_W    = (const float*)d_in[5];
  const float* d_a    = (const float*)d_in[6];
  const float* c_bn_g = (const float*)d_in[7];
  const float* c_bn_b = (const float*)d_in[8];
  const float* d_bn_g = (const float*)d_in[9];
  const float* d_bn_b = (const float*)d_in[10];
  float* out = (float*)d_out;
  float* out_d = out + (size_t)4096 * 256;

  char* w = (char*)d_ws;
  size_t off = 0;
  auto take = [&](size_t b) -> char* {
    char* p = w + off;
    off += (b + 255) & ~(size_t)255;
    return p;
  };
  unsigned short* Sbt_c = (unsigned short*)take(256 * 2048 * 2);
  unsigned short* Sbt_d = (unsigned short*)take(256 * 4096 * 2);
  float* et2_c  = (float*)take(4096 * 8 * 4);
  float* es2t_c = (float*)take(8 * 2048 * 4);
  float* et2_d  = (float*)take(2048 * 8 * 4);
  float* es2t_d = (float*)take(8 * 4096 * 4);
  float* wa_c   = (float*)take(8 * 256 * 4);
  float* wa_d   = (float*)take(8 * 256 * 4);
  unsigned* adjP  = (unsigned*)take(4096 * 64 * 4);
  unsigned* adjPT = (unsigned*)take(2048 * 128 * 4);

  // choose chunk count by available scratch
  const size_t base = off;
  auto total_need = [&](int cc) -> size_t {
    size_t pd = ((size_t)cc * 4096 * 8 * 4 + 256) + ((size_t)cc * 2048 * 8 * 4 + 256);
    size_t vol = (cc > 1) ? (size_t)cc * (4096 + 2048) * 256 * 4
                          : (size_t)(2048 + 4096) * 256 * 4;
    return base + pd + vol + 1024;
  };
  int cc = 1;
  if (ws_size >= total_need(4)) cc = 4;
  else if (ws_size >= total_need(2)) cc = 2;

  float* pden_c = (float*)take((size_t)cc * 4096 * 8 * 4);
  float* pden_d = (float*)take((size_t)cc * 2048 * 8 * 4);
  // volatile region: S_c/S_d live during prep; pnum aliases it afterwards
  char* vol = w + off;
  float* S_c = (float*)vol;
  float* S_d = S_c + (size_t)2048 * 256;
  float* pnum_c = (float*)vol;
  float* pnum_d = pnum_c + (size_t)cc * 4096 * 256;

  dim3 blk(256);
  pack_adj<<<dim3(32, 64), blk, 0, stream>>>(adj, adjP, adjPT);
  wa_kernel<<<8, blk, 0, stream>>>(c_W, c_a, wa_c);
  wa_kernel<<<8, blk, 0, stream>>>(d_W, d_a, wa_d);
  gemm_abt<<<dim3(4, 32), blk, 0, stream>>>(d_feat, c_W, S_c, 2048, 256, 256);
  gemm_abt<<<dim3(4, 64), blk, 0, stream>>>(c_feat, d_W, S_d, 4096, 256, 256);
  et_kernel<<<128, blk, 0, stream>>>(c_feat, wa_c, et2_c, 4096);
  et_kernel<<<64,  blk, 0, stream>>>(d_feat, wa_d, et2_d, 2048);
  escore_t<<<64,  blk, 0, stream>>>(S_c, c_a, es2t_c, 2048, 11);
  escore_t<<<128, blk, 0, stream>>>(S_d, d_a, es2t_d, 4096, 12);
  sconvert<<<dim3(32, 4), blk, 0, stream>>>(S_c, Sbt_c, 2048);
  sconvert<<<dim3(64, 4), blk, 0, stream>>>(S_d, Sbt_d, 4096);

  if (cc == 1) {
    fused_attn<1><<<dim3(256, 1), blk, 0, stream>>>(
        et2_c, es2t_c, adjP, Sbt_c, nullptr, nullptr, out,
        c_bn_g, c_bn_b, 2048, 2048);
    fused_attn<1><<<dim3(128, 1), blk, 0, stream>>>(
        et2_d, es2t_d, adjPT, Sbt_d, nullptr, nullptr, out_d,
        d_bn_g, d_bn_b, 4096, 4096);
  } else {
    fused_attn<0><<<dim3(256, cc), blk, 0, stream>>>(
        et2_c, es2t_c, adjP, Sbt_c, pnum_c, pden_c, nullptr,
        c_bn_g, c_bn_b, 2048, 2048 / cc);
    fused_attn<0><<<dim3(128, cc), blk, 0, stream>>>(
        et2_d, es2t_d, adjPT, Sbt_d, pnum_d, pden_d, nullptr,
        d_bn_g, d_bn_b, 4096, 4096 / cc);
    finalize_k<<<1024, blk, 0, stream>>>(pnum_c, pden_c, out, c_bn_g, c_bn_b, 4096, cc);
    finalize_k<<<512,  blk, 0, stream>>>(pnum_d, pden_d, out_d, d_bn_g, d_bn_b, 2048, cc);
  }
}

// Round 4
// 151.925 us; speedup vs baseline: 8.4158x; 1.2250x over previous
//
#include <hip/hip_runtime.h>
#include <hip/hip_bf16.h>

#define L2E 1.4426950408889634f
#define BNF 0.99999500003749969f   // 1/sqrt(1+1e-5)

typedef __attribute__((ext_vector_type(4))) float f4;
typedef __attribute__((ext_vector_type(4))) float f32x4;
typedef __attribute__((ext_vector_type(8))) short bfrag;   // 8 bf16 = 4 VGPRs

__device__ __forceinline__ int cvtpk(float lo, float hi) {
  int r;
  asm("v_cvt_pk_bf16_f32 %0, %1, %2" : "=v"(r) : "v"(lo), "v"(hi));
  return r;
}

// ------- wa[h][k] = L2E * sum_{d<32} a[h*64+d] * W[(h*32+d)*256 + k] -------
// idx < 2048 -> c-side, else d-side
__global__ __launch_bounds__(256) void wa_both(
    const float* __restrict__ c_W, const float* __restrict__ c_a,
    const float* __restrict__ d_W, const float* __restrict__ d_a,
    float* __restrict__ wa_c, float* __restrict__ wa_d) {
  int idx = blockIdx.x * 256 + threadIdx.x;   // 4096
  bool cs = idx < 2048;
  int i2 = idx & 2047;
  int h = i2 >> 8, k = i2 & 255;
  const float* W = cs ? c_W : d_W;
  const float* a = cs ? c_a : d_a;
  float s = 0.f;
#pragma unroll 8
  for (int d = 0; d < 32; ++d)
    s = fmaf(a[h * 64 + d], W[(size_t)(h * 32 + d) * 256 + k], s);
  (cs ? wa_c : wa_d)[i2] = s * L2E;
}

// ------- et2[r][h] = sum_k X[r][k] * wa[h][k]  (wa pre-scaled by L2E) -------
__global__ __launch_bounds__(256) void et_both(
    const float* __restrict__ c_feat, const float* __restrict__ wa_c,
    const float* __restrict__ d_feat, const float* __restrict__ wa_d,
    float* __restrict__ et2_c, float* __restrict__ et2_d) {
  int b = blockIdx.x;
  bool cs = b < 128;
  int idx = (cs ? b : b - 128) * 256 + threadIdx.x;
  const float* X = cs ? c_feat : d_feat;
  const float* wa = cs ? wa_c : wa_d;
  float* et2 = cs ? et2_c : et2_d;
  int r = idx >> 3, h = idx & 7;
  const float* xp = X + (size_t)r * 256;
  const float* ap = wa + h * 256;
  float s = 0.f;
#pragma unroll 16
  for (int k = 0; k < 256; k += 4) {
    f4 xv = *(const f4*)(xp + k);
    f4 av = *(const f4*)(ap + k);
    s = fmaf(xv.x, av.x, s); s = fmaf(xv.y, av.y, s);
    s = fmaf(xv.z, av.z, s); s = fmaf(xv.w, av.w, s);
  }
  et2[idx] = s;
}

// ------- pack adjacency into bitmasks: adjP[n][m/32], adjPT[m][n/32] -------
__global__ __launch_bounds__(256) void pack_adj(
    const int* __restrict__ adj, unsigned* __restrict__ adjP,
    unsigned* __restrict__ adjPT) {
  __shared__ int s[64][65];
  const int n0 = blockIdx.y * 64, m0 = blockIdx.x * 64;
  const int t = threadIdx.x;
#pragma unroll
  for (int i = 0; i < 4; ++i) {
    int idx = t + i * 256;
    int r = idx >> 4, c4 = (idx & 15) * 4;
    int4 v = *(const int4*)(adj + (size_t)(n0 + r) * 2048 + m0 + c4);
    s[r][c4 + 0] = v.x; s[r][c4 + 1] = v.y;
    s[r][c4 + 2] = v.z; s[r][c4 + 3] = v.w;
  }
  __syncthreads();
  const int w = t >> 6, l = t & 63;
#pragma unroll 4
  for (int rr = 0; rr < 16; ++rr) {
    int r = w * 16 + rr;
    unsigned long long b = __ballot(s[r][l] != 0);
    if (l == 0) {
      adjP[(size_t)(n0 + r) * 64 + (m0 >> 5)] = (unsigned)b;
      adjP[(size_t)(n0 + r) * 64 + (m0 >> 5) + 1] = (unsigned)(b >> 32);
    }
  }
#pragma unroll 4
  for (int cc = 0; cc < 16; ++cc) {
    int m = m0 + w * 16 + cc;
    unsigned long long b = __ballot(s[l][w * 16 + cc] != 0);
    if (l == 0) {
      adjPT[(size_t)m * 128 + (n0 >> 5)] = (unsigned)b;
      adjPT[(size_t)m * 128 + (n0 >> 5) + 1] = (unsigned)(b >> 32);
    }
  }
}

// ------- GEMM S = A @ W^T with fused epilogue: Sbt (bf16, transposed) + es2t -------
// blocks [0,128): c-side (A=d_feat, 2048 rows); [128,384): d-side (A=c_feat, 4096)
__global__ __launch_bounds__(256) void gemm_both(
    const float* __restrict__ c_feat, const float* __restrict__ d_feat,
    const float* __restrict__ c_W, const float* __restrict__ d_W,
    const float* __restrict__ c_a, const float* __restrict__ d_a,
    unsigned short* __restrict__ Sbt_c, unsigned short* __restrict__ Sbt_d,
    float* __restrict__ es2t_c, float* __restrict__ es2t_d) {
  __shared__ __align__(16) float As[16][64];
  __shared__ __align__(16) float Bs[16][64];
  const int b = blockIdx.x;
  const bool cs = b < 128;
  const int bb = cs ? b : b - 128;
  const float* A = cs ? d_feat : c_feat;
  const float* B = cs ? c_W : d_W;
  const float* av = cs ? c_a : d_a;
  unsigned short* Sbt = cs ? Sbt_c : Sbt_d;
  float* es2t = cs ? es2t_c : es2t_d;
  const int Mrows = cs ? 2048 : 4096;
  const int row0 = (bb >> 2) * 64, col0 = (bb & 3) * 64;
  const int t = threadIdx.x;
  const int ty = t >> 4, tx = t & 15;
  const int lr = t >> 2, lk = (t & 3) * 4;
  float acc[4][4] = {};
  for (int k0 = 0; k0 < 256; k0 += 16) {
    float4 avv = *(const float4*)(A + (size_t)(row0 + lr) * 256 + k0 + lk);
    float4 bvv = *(const float4*)(B + (size_t)(col0 + lr) * 256 + k0 + lk);
    __syncthreads();
    As[lk + 0][lr] = avv.x; As[lk + 1][lr] = avv.y;
    As[lk + 2][lr] = avv.z; As[lk + 3][lr] = avv.w;
    Bs[lk + 0][lr] = bvv.x; Bs[lk + 1][lr] = bvv.y;
    Bs[lk + 2][lr] = bvv.z; Bs[lk + 3][lr] = bvv.w;
    __syncthreads();
#pragma unroll
    for (int kk = 0; kk < 16; ++kk) {
      float4 a4 = *(const float4*)&As[kk][ty * 4];
      float4 b4 = *(const float4*)&Bs[kk][tx * 4];
      const float aa[4] = {a4.x, a4.y, a4.z, a4.w};
      const float bb4[4] = {b4.x, b4.y, b4.z, b4.w};
#pragma unroll
      for (int i = 0; i < 4; ++i)
#pragma unroll
        for (int j = 0; j < 4; ++j)
          acc[i][j] = fmaf(aa[i], bb4[j], acc[i][j]);
    }
  }
  // --- epilogue (a): es2t[h][m] partials, reduced over the 8-lane tx-octet ---
  f4 aw = *(const f4*)(av + ((col0 >> 5) + (tx >> 3)) * 64 + 32 + (tx & 7) * 4);
  float part[4];
#pragma unroll
  for (int i = 0; i < 4; ++i)
    part[i] = acc[i][0] * aw.x + acc[i][1] * aw.y + acc[i][2] * aw.z + acc[i][3] * aw.w;
#pragma unroll
  for (int i = 0; i < 4; ++i) {
    part[i] += __shfl_xor(part[i], 1);
    part[i] += __shfl_xor(part[i], 2);
    part[i] += __shfl_xor(part[i], 4);
  }
  if ((tx & 7) == 0) {
    int h = (col0 >> 5) + (tx >> 3);
    f4 o = {part[0] * L2E, part[1] * L2E, part[2] * L2E, part[3] * L2E};
    *(f4*)(es2t + (size_t)h * Mrows + row0 + ty * 4) = o;
  }
  // --- epilogue (b): Sbt[c][m] bf16 transposed ---
#pragma unroll
  for (int j = 0; j < 4; ++j) {
    uint2 u;
    u.x = (unsigned)cvtpk(acc[0][j], acc[1][j]);
    u.y = (unsigned)cvtpk(acc[2][j], acc[3][j]);
    *(uint2*)(Sbt + (size_t)(col0 + tx * 4 + j) * Mrows + row0 + ty * 4) = u;
  }
}

// ------- fused attention: P-gen (exp2, masked) -> MFMA PV + MFMA den -------
__device__ __forceinline__ bfrag make_pfrag(float et, const float* es,
                                            unsigned bits) {
  f4 e0 = *(const f4*)es;
  f4 e1 = *(const f4*)(es + 4);
  float xv[8] = {e0.x, e0.y, e0.z, e0.w, e1.x, e1.y, e1.z, e1.w};
  float p[8];
#pragma unroll
  for (int e = 0; e < 8; ++e) {
    float x = et + xv[e];
    x = fmaxf(x, 0.2f * x);                 // LeakyReLU (exp2 domain)
    float pe = __builtin_amdgcn_exp2f(x);
    p[e] = ((bits >> e) & 1u) ? pe : 0.f;
  }
  union { bfrag v; int i[4]; } u;
#pragma unroll
  for (int e = 0; e < 4; ++e) u.i[e] = cvtpk(p[2 * e], p[2 * e + 1]);
  return u.v;
}

template <int FINAL>
__global__ __launch_bounds__(256) void fused_attn(
    const float* __restrict__ et2_c, const float* __restrict__ es2t_c,
    const unsigned* __restrict__ adjP, const unsigned short* __restrict__ Sbt_c,
    float* __restrict__ pnum_c, float* __restrict__ pden_c,
    const float* __restrict__ et2_d, const float* __restrict__ es2t_d,
    const unsigned* __restrict__ adjPT, const unsigned short* __restrict__ Sbt_d,
    float* __restrict__ pnum_d, float* __restrict__ pden_d,
    float* __restrict__ out,
    const float* __restrict__ gc, const float* __restrict__ bc,
    const float* __restrict__ gd, const float* __restrict__ bd,
    int NBC, int CH_C, int CH_D) {
  const int b = blockIdx.x;
  const bool cs = b < NBC;
  const int bb = cs ? b : b - NBC;
  const int n0 = (cs ? (bb & 255) : (bb & 127)) * 16;
  const int chunk = cs ? (bb >> 8) : (bb >> 7);
  const int M = cs ? 2048 : 4096;
  const int ROWS = cs ? 4096 : 2048;
  const int CH = cs ? CH_C : CH_D;
  const float* et2 = cs ? et2_c : et2_d;
  const float* es2t = cs ? es2t_c : es2t_d;
  const unsigned* adjPk = cs ? adjP : adjPT;
  const unsigned short* Sbt = cs ? Sbt_c : Sbt_d;
  float* pnum = cs ? pnum_c : pnum_d;
  float* pden = cs ? pden_c : pden_d;
  const float* bng = cs ? gc : gd;
  const float* bnb = cs ? bc : bd;
  float* outp = cs ? out : out + (size_t)4096 * 256;

  const int mstart = chunk * CH, mend = mstart + CH;
  const int Mw = M >> 5;
  const int tid = threadIdx.x;
  const int w = tid >> 6, l = tid & 63;
  const int g = l >> 4, c16 = l & 15;
  const int hA = w * 2, hB = w * 2 + 1;
  const int row = n0 + c16;
  const float etA = et2[row * 8 + hA];
  const float etB = et2[row * 8 + hB];
  const unsigned* adjrow = adjPk + (size_t)row * Mw;
  const float* esArow = es2t + (size_t)hA * M;
  const float* esBrow = es2t + (size_t)hB * M;
  const unsigned short* SbtA0 = Sbt + (size_t)(hA * 32 + c16) * M;
  const unsigned short* SbtA1 = Sbt + (size_t)(hA * 32 + 16 + c16) * M;
  const unsigned short* SbtB0 = Sbt + (size_t)(hB * 32 + c16) * M;
  const unsigned short* SbtB1 = Sbt + (size_t)(hB * 32 + 16 + c16) * M;
  f32x4 accA0 = {0.f, 0.f, 0.f, 0.f}, accA1 = accA0, denA = accA0;
  f32x4 accB0 = accA0, accB1 = accA0, denB = accA0;
  union { bfrag v; int i[4]; } uo;
#pragma unroll
  for (int e = 0; e < 4; ++e) uo.i[e] = 0x3F803F80;   // bf16(1.0) pairs
  const bfrag ones = uo.v;

  for (int m0 = mstart; m0 < mend; m0 += 32) {
    const unsigned bits = (adjrow[m0 >> 5] >> (g * 8)) & 0xffu;
    const int mo = m0 + g * 8;
    bfrag aA = make_pfrag(etA, esArow + mo, bits);
    bfrag aB = make_pfrag(etB, esBrow + mo, bits);
    bfrag bA0 = *(const bfrag*)(SbtA0 + mo);
    bfrag bA1 = *(const bfrag*)(SbtA1 + mo);
    bfrag bB0 = *(const bfrag*)(SbtB0 + mo);
    bfrag bB1 = *(const bfrag*)(SbtB1 + mo);
    accA0 = __builtin_amdgcn_mfma_f32_16x16x32_bf16(aA, bA0, accA0, 0, 0, 0);
    accA1 = __builtin_amdgcn_mfma_f32_16x16x32_bf16(aA, bA1, accA1, 0, 0, 0);
    denA  = __builtin_amdgcn_mfma_f32_16x16x32_bf16(aA, ones, denA, 0, 0, 0);
    accB0 = __builtin_amdgcn_mfma_f32_16x16x32_bf16(aB, bB0, accB0, 0, 0, 0);
    accB1 = __builtin_amdgcn_mfma_f32_16x16x32_bf16(aB, bB1, accB1, 0, 0, 0);
    denB  = __builtin_amdgcn_mfma_f32_16x16x32_bf16(aB, ones, denB, 0, 0, 0);
  }

  // C/D layout: col = c16, row = g*4 + reg
#define EPILOGUE(acc0, acc1, den, h)                                          \
  {                                                                           \
    const int c0 = (h) * 32 + c16, c1 = (h) * 32 + 16 + c16;                  \
    if (FINAL) {                                                              \
      const float g0 = bng[c0] * BNF, b0 = bnb[c0];                           \
      const float g1 = bng[c1] * BNF, b1 = bnb[c1];                           \
      _Pragma("unroll") for (int i = 0; i < 4; ++i) {                         \
        float rs = 1.f / fmaxf(den[i], 1e-30f);                               \
        float* op = outp + (size_t)(n0 + g * 4 + i) * 256;                    \
        op[c0] = fmaxf(fmaf(acc0[i] * rs, g0, b0), 0.f);                      \
        op[c1] = fmaxf(fmaf(acc1[i] * rs, g1, b1), 0.f);                      \
      }                                                                       \
    } else {                                                                  \
      _Pragma("unroll") for (int i = 0; i < 4; ++i) {                         \
        size_t rr = (size_t)chunk * ROWS + n0 + g * 4 + i;                    \
        pnum[rr * 256 + c0] = acc0[i];                                        \
        pnum[rr * 256 + c1] = acc1[i];                                        \
        if (c16 == 0) pden[rr * 8 + (h)] = den[i];                            \
      }                                                                       \
    }                                                                         \
  }
  EPILOGUE(accA0, accA1, denA, hA)
  EPILOGUE(accB0, accB1, denB, hB)
#undef EPILOGUE
}

// ------- finalize: sum partials, divide, BN, ReLU (both sides) -------
__global__ __launch_bounds__(256) void finalize_k(
    const float* __restrict__ pnum_c, const float* __restrict__ pden_c,
    const float* __restrict__ pnum_d, const float* __restrict__ pden_d,
    float* __restrict__ out,
    const float* __restrict__ gc, const float* __restrict__ bc,
    const float* __restrict__ gd, const float* __restrict__ bd,
    int cc_c, int cc_d) {
  const int b = blockIdx.x;
  const bool cs = b < 1024;
  const int idx = (cs ? b : b - 1024) * 256 + threadIdx.x;
  const int rows = cs ? 4096 : 2048;
  const int cc = cs ? cc_c : cc_d;
  const float* pnum = cs ? pnum_c : pnum_d;
  const float* pden = cs ? pden_c : pden_d;
  const float* bng = cs ? gc : gd;
  const float* bnb = cs ? bc : bd;
  float* outp = cs ? out : out + (size_t)4096 * 256;
  int r = idx >> 6, c4 = (idx & 63) * 4;
  int h = c4 >> 5;
  f4 num = {0.f, 0.f, 0.f, 0.f};
  float den = 0.f;
  for (int c = 0; c < cc; ++c) {
    size_t rr = (size_t)c * rows + r;
    num += *(const f4*)(pnum + rr * 256 + c4);
    den += pden[rr * 8 + h];
  }
  float rs = 1.f / fmaxf(den, 1e-30f);
  f4 gm = *(const f4*)(bng + c4);
  f4 bb = *(const f4*)(bnb + c4);
  f4 o;
  o.x = fmaxf(fmaf(num.x * rs, gm.x * BNF, bb.x), 0.f);
  o.y = fmaxf(fmaf(num.y * rs, gm.y * BNF, bb.y), 0.f);
  o.z = fmaxf(fmaf(num.z * rs, gm.z * BNF, bb.z), 0.f);
  o.w = fmaxf(fmaf(num.w * rs, gm.w * BNF, bb.w), 0.f);
  *(f4*)(outp + (size_t)r * 256 + c4) = o;
}

extern "C" void kernel_launch(void* const* d_in, const int* in_sizes, int n_in,
                              void* d_out, int out_size, void* d_ws, size_t ws_size,
                              hipStream_t stream) {
  const float* c_feat = (const float*)d_in[0];   // [4096,256]
  const float* d_feat = (const float*)d_in[1];   // [2048,256]
  const int*   adj    = (const int*)d_in[2];     // [4096,2048]
  const float* c_W    = (const float*)d_in[3];
  const float* c_a    = (const float*)d_in[4];   // [8,64]
  const float* d_W    = (const float*)d_in[5];
  const float* d_a    = (const float*)d_in[6];
  const float* c_bn_g = (const float*)d_in[7];
  const float* c_bn_b = (const float*)d_in[8];
  const float* d_bn_g = (const float*)d_in[9];
  const float* d_bn_b = (const float*)d_in[10];
  float* out = (float*)d_out;

  char* w = (char*)d_ws;
  size_t off = 0;
  auto take = [&](size_t bytes) -> char* {
    char* p = w + off;
    off += (bytes + 255) & ~(size_t)255;
    return p;
  };
  unsigned short* Sbt_c = (unsigned short*)take(256 * 2048 * 2);
  unsigned short* Sbt_d = (unsigned short*)take(256 * 4096 * 2);
  float* et2_c  = (float*)take(4096 * 8 * 4);
  float* es2t_c = (float*)take(8 * 2048 * 4);
  float* et2_d  = (float*)take(2048 * 8 * 4);
  float* es2t_d = (float*)take(8 * 4096 * 4);
  float* wa_c   = (float*)take(8 * 256 * 4);
  float* wa_d   = (float*)take(8 * 256 * 4);
  unsigned* adjP  = (unsigned*)take(4096 * 64 * 4);
  unsigned* adjPT = (unsigned*)take(2048 * 128 * 4);

  // chunk-count ladder by available scratch
  const size_t base = off;
  const size_t PC = (size_t)4096 * 256 * 4, PD = (size_t)2048 * 256 * 4;
  const size_t DC = 4096 * 8 * 4, DD = 2048 * 8 * 4;
  auto need = [&](int a, int b2) -> size_t {
    return base + (size_t)a * (PC + DC) + (size_t)b2 * (PD + DD) + 4096;
  };
  int ccc = 0, ccd = 0;
  if (ws_size >= need(4, 8))      { ccc = 4; ccd = 8; }
  else if (ws_size >= need(4, 4)) { ccc = 4; ccd = 4; }
  else if (ws_size >= need(2, 4)) { ccc = 2; ccd = 4; }
  else if (ws_size >= need(2, 2)) { ccc = 2; ccd = 2; }

  float* pden_c = nullptr; float* pden_d = nullptr;
  float* pnum_c = nullptr; float* pnum_d = nullptr;
  if (ccc) {
    pden_c = (float*)take((size_t)ccc * DC);
    pden_d = (float*)take((size_t)ccd * DD);
    pnum_c = (float*)take((size_t)ccc * PC);
    pnum_d = (float*)take((size_t)ccd * PD);
  }

  dim3 blk(256);
  wa_both<<<16, blk, 0, stream>>>(c_W, c_a, d_W, d_a, wa_c, wa_d);
  pack_adj<<<dim3(32, 64), blk, 0, stream>>>(adj, adjP, adjPT);
  gemm_both<<<384, blk, 0, stream>>>(c_feat, d_feat, c_W, d_W, c_a, d_a,
                                     Sbt_c, Sbt_d, es2t_c, es2t_d);
  et_both<<<192, blk, 0, stream>>>(c_feat, wa_c, d_feat, wa_d, et2_c, et2_d);

  if (ccc) {
    fused_attn<0><<<256 * ccc + 128 * ccd, blk, 0, stream>>>(
        et2_c, es2t_c, adjP, Sbt_c, pnum_c, pden_c,
        et2_d, es2t_d, adjPT, Sbt_d, pnum_d, pden_d,
        nullptr, c_bn_g, c_bn_b, d_bn_g, d_bn_b,
        256 * ccc, 2048 / ccc, 4096 / ccd);
    finalize_k<<<1536, blk, 0, stream>>>(pnum_c, pden_c, pnum_d, pden_d, out,
                                         c_bn_g, c_bn_b, d_bn_g, d_bn_b, ccc, ccd);
  } else {
    fused_attn<1><<<384, blk, 0, stream>>>(
        et2_c, es2t_c, adjP, Sbt_c, nullptr, nullptr,
        et2_d, es2t_d, adjPT, Sbt_d, nullptr, nullptr,
        out, c_bn_g, c_bn_b, d_bn_g, d_bn_b, 256, 2048, 4096);
  }
}

// Round 6
// 145.291 us; speedup vs baseline: 8.8002x; 1.0457x over previous
//
#include <hip/hip_runtime.h>
#include <hip/hip_bf16.h>

#define L2E 1.4426950408889634f
#define BNF 0.99999500003749969f   // 1/sqrt(1+1e-5)

typedef __attribute__((ext_vector_type(4))) float f4;
typedef __attribute__((ext_vector_type(4))) float f32x4;
typedef __attribute__((ext_vector_type(8))) short bfrag;   // 8 bf16 = 4 VGPRs

__device__ __forceinline__ int cvtpk(float lo, float hi) {
  int r;
  asm("v_cvt_pk_bf16_f32 %0, %1, %2" : "=v"(r) : "v"(lo), "v"(hi));
  return r;
}

// ------- wa[h][k] = L2E * sum_{d<32} a[h*64+d] * W[(h*32+d)*256 + k] -------
__global__ __launch_bounds__(256) void wa_both(
    const float* __restrict__ c_W, const float* __restrict__ c_a,
    const float* __restrict__ d_W, const float* __restrict__ d_a,
    float* __restrict__ wa_c, float* __restrict__ wa_d) {
  int idx = blockIdx.x * 256 + threadIdx.x;   // 4096
  bool cs = idx < 2048;
  int i2 = idx & 2047;
  int h = i2 >> 8, k = i2 & 255;
  const float* W = cs ? c_W : d_W;
  const float* a = cs ? c_a : d_a;
  float s = 0.f;
#pragma unroll 8
  for (int d = 0; d < 32; ++d)
    s = fmaf(a[h * 64 + d], W[(size_t)(h * 32 + d) * 256 + k], s);
  (cs ? wa_c : wa_d)[i2] = s * L2E;
}

// ------- et2[r][h] = sum_k X[r][k] * wa[h][k]  (wa pre-scaled by L2E) -------
__global__ __launch_bounds__(256) void et_both(
    const float* __restrict__ c_feat, const float* __restrict__ wa_c,
    const float* __restrict__ d_feat, const float* __restrict__ wa_d,
    float* __restrict__ et2_c, float* __restrict__ et2_d) {
  int b = blockIdx.x;
  bool cs = b < 128;
  int idx = (cs ? b : b - 128) * 256 + threadIdx.x;
  const float* X = cs ? c_feat : d_feat;
  const float* wa = cs ? wa_c : wa_d;
  float* et2 = cs ? et2_c : et2_d;
  int r = idx >> 3, h = idx & 7;
  const float* xp = X + (size_t)r * 256;
  const float* ap = wa + h * 256;
  float s = 0.f;
#pragma unroll 16
  for (int k = 0; k < 256; k += 4) {
    f4 xv = *(const f4*)(xp + k);
    f4 av = *(const f4*)(ap + k);
    s = fmaf(xv.x, av.x, s); s = fmaf(xv.y, av.y, s);
    s = fmaf(xv.z, av.z, s); s = fmaf(xv.w, av.w, s);
  }
  et2[idx] = s;
}

// ------- pack adjacency into bitmasks: adjP[n][m/32], adjPT[m][n/32] -------
__global__ __launch_bounds__(256) void pack_adj(
    const int* __restrict__ adj, unsigned* __restrict__ adjP,
    unsigned* __restrict__ adjPT) {
  __shared__ int s[64][65];
  const int n0 = blockIdx.y * 64, m0 = blockIdx.x * 64;
  const int t = threadIdx.x;
#pragma unroll
  for (int i = 0; i < 4; ++i) {
    int idx = t + i * 256;
    int r = idx >> 4, c4 = (idx & 15) * 4;
    int4 v = *(const int4*)(adj + (size_t)(n0 + r) * 2048 + m0 + c4);
    s[r][c4 + 0] = v.x; s[r][c4 + 1] = v.y;
    s[r][c4 + 2] = v.z; s[r][c4 + 3] = v.w;
  }
  __syncthreads();
  const int w = t >> 6, l = t & 63;
#pragma unroll 4
  for (int rr = 0; rr < 16; ++rr) {
    int r = w * 16 + rr;
    unsigned long long b = __ballot(s[r][l] != 0);
    if (l == 0) {
      adjP[(size_t)(n0 + r) * 64 + (m0 >> 5)] = (unsigned)b;
      adjP[(size_t)(n0 + r) * 64 + (m0 >> 5) + 1] = (unsigned)(b >> 32);
    }
  }
#pragma unroll 4
  for (int cc = 0; cc < 16; ++cc) {
    int m = m0 + w * 16 + cc;
    unsigned long long b = __ballot(s[l][w * 16 + cc] != 0);
    if (l == 0) {
      adjPT[(size_t)m * 128 + (n0 >> 5)] = (unsigned)b;
      adjPT[(size_t)m * 128 + (n0 >> 5) + 1] = (unsigned)(b >> 32);
    }
  }
}

// ------- GEMM S = A @ W^T with fused epilogue: Sbt (bf16, transposed) + es2t -------
__global__ __launch_bounds__(256) void gemm_both(
    const float* __restrict__ c_feat, const float* __restrict__ d_feat,
    const float* __restrict__ c_W, const float* __restrict__ d_W,
    const float* __restrict__ c_a, const float* __restrict__ d_a,
    unsigned short* __restrict__ Sbt_c, unsigned short* __restrict__ Sbt_d,
    float* __restrict__ es2t_c, float* __restrict__ es2t_d) {
  __shared__ __align__(16) float As[16][64];
  __shared__ __align__(16) float Bs[16][64];
  const int b = blockIdx.x;
  const bool cs = b < 128;
  const int bb = cs ? b : b - 128;
  const float* A = cs ? d_feat : c_feat;
  const float* B = cs ? c_W : d_W;
  const float* av = cs ? c_a : d_a;
  unsigned short* Sbt = cs ? Sbt_c : Sbt_d;
  float* es2t = cs ? es2t_c : es2t_d;
  const int Mrows = cs ? 2048 : 4096;
  const int row0 = (bb >> 2) * 64, col0 = (bb & 3) * 64;
  const int t = threadIdx.x;
  const int ty = t >> 4, tx = t & 15;
  const int lr = t >> 2, lk = (t & 3) * 4;
  float acc[4][4] = {};
  for (int k0 = 0; k0 < 256; k0 += 16) {
    float4 avv = *(const float4*)(A + (size_t)(row0 + lr) * 256 + k0 + lk);
    float4 bvv = *(const float4*)(B + (size_t)(col0 + lr) * 256 + k0 + lk);
    __syncthreads();
    As[lk + 0][lr] = avv.x; As[lk + 1][lr] = avv.y;
    As[lk + 2][lr] = avv.z; As[lk + 3][lr] = avv.w;
    Bs[lk + 0][lr] = bvv.x; Bs[lk + 1][lr] = bvv.y;
    Bs[lk + 2][lr] = bvv.z; Bs[lk + 3][lr] = bvv.w;
    __syncthreads();
#pragma unroll
    for (int kk = 0; kk < 16; ++kk) {
      float4 a4 = *(const float4*)&As[kk][ty * 4];
      float4 b4 = *(const float4*)&Bs[kk][tx * 4];
      const float aa[4] = {a4.x, a4.y, a4.z, a4.w};
      const float bb4[4] = {b4.x, b4.y, b4.z, b4.w};
#pragma unroll
      for (int i = 0; i < 4; ++i)
#pragma unroll
        for (int j = 0; j < 4; ++j)
          acc[i][j] = fmaf(aa[i], bb4[j], acc[i][j]);
    }
  }
  // epilogue (a): es2t partials reduced over the 8-lane tx-octet
  f4 aw = *(const f4*)(av + ((col0 >> 5) + (tx >> 3)) * 64 + 32 + (tx & 7) * 4);
  float part[4];
#pragma unroll
  for (int i = 0; i < 4; ++i)
    part[i] = acc[i][0] * aw.x + acc[i][1] * aw.y + acc[i][2] * aw.z + acc[i][3] * aw.w;
#pragma unroll
  for (int i = 0; i < 4; ++i) {
    part[i] += __shfl_xor(part[i], 1);
    part[i] += __shfl_xor(part[i], 2);
    part[i] += __shfl_xor(part[i], 4);
  }
  if ((tx & 7) == 0) {
    int h = (col0 >> 5) + (tx >> 3);
    f4 o = {part[0] * L2E, part[1] * L2E, part[2] * L2E, part[3] * L2E};
    *(f4*)(es2t + (size_t)h * Mrows + row0 + ty * 4) = o;
  }
  // epilogue (b): Sbt[c][m] bf16 transposed
#pragma unroll
  for (int j = 0; j < 4; ++j) {
    uint2 u;
    u.x = (unsigned)cvtpk(acc[0][j], acc[1][j]);
    u.y = (unsigned)cvtpk(acc[2][j], acc[3][j]);
    *(uint2*)(Sbt + (size_t)(col0 + tx * 4 + j) * Mrows + row0 + ty * 4) = u;
  }
}

// ------- fused attention: P-gen (exp2, masked AFTER exp2, R4 semantics) -------
__device__ __forceinline__ bfrag make_pfrag2(float et, f4 e0, f4 e1,
                                             unsigned bits) {
  float xv[8] = {e0.x, e0.y, e0.z, e0.w, e1.x, e1.y, e1.z, e1.w};
  float p[8];
#pragma unroll
  for (int e = 0; e < 8; ++e) {
    float x = et + xv[e];
    x = fmaxf(x, 0.2f * x);                 // LeakyReLU (exp2 domain)
    float pe = __builtin_amdgcn_exp2f(x);
    p[e] = ((bits >> e) & 1u) ? pe : 0.f;   // mask result (R4-proven)
  }
  union { bfrag v; int i[4]; } u;
#pragma unroll
  for (int e = 0; e < 4; ++e) u.i[e] = cvtpk(p[2 * e], p[2 * e + 1]);
  return u.v;
}

#define MFMA16(a, b, c) __builtin_amdgcn_mfma_f32_16x16x32_bf16(a, b, c, 0, 0, 0)

template <int FINAL>
__global__ __launch_bounds__(256) void fused_attn(
    const float* __restrict__ et2_c, const float* __restrict__ es2t_c,
    const unsigned* __restrict__ adjP, const unsigned short* __restrict__ Sbt_c,
    float* __restrict__ pnum_c, float* __restrict__ pden_c,
    const float* __restrict__ et2_d, const float* __restrict__ es2t_d,
    const unsigned* __restrict__ adjPT, const unsigned short* __restrict__ Sbt_d,
    float* __restrict__ pnum_d, float* __restrict__ pden_d,
    float* __restrict__ out,
    const float* __restrict__ gc, const float* __restrict__ bc,
    const float* __restrict__ gd, const float* __restrict__ bd,
    int NBC, int CH_C, int CH_D) {
  const int b = blockIdx.x;
  const bool cs = b < NBC;
  const int bb = cs ? b : b - NBC;
  const int n0 = (cs ? (bb & 255) : (bb & 127)) * 16;
  const int chunk = cs ? (bb >> 8) : (bb >> 7);
  const int M = cs ? 2048 : 4096;
  const int ROWS = cs ? 4096 : 2048;
  const int CH = cs ? CH_C : CH_D;
  const float* et2 = cs ? et2_c : et2_d;
  const float* es2t = cs ? es2t_c : es2t_d;
  const unsigned* adjPk = cs ? adjP : adjPT;
  const unsigned short* Sbt = cs ? Sbt_c : Sbt_d;
  float* pnum = cs ? pnum_c : pnum_d;
  float* pden = cs ? pden_c : pden_d;
  const float* bng = cs ? gc : gd;
  const float* bnb = cs ? bc : bd;
  float* outp = cs ? out : out + (size_t)4096 * 256;

  const int mstart = chunk * CH, mend = mstart + CH;
  const int Mw = M >> 5;
  const int tid = threadIdx.x;
  const int w = tid >> 6, l = tid & 63;
  const int g = l >> 4, c16 = l & 15;
  const int hA = w * 2, hB = w * 2 + 1;
  const int row = n0 + c16;
  const float etA = et2[row * 8 + hA];
  const float etB = et2[row * 8 + hB];
  const unsigned* adjrow = adjPk + (size_t)row * Mw;
  const float* esArow = es2t + (size_t)hA * M;
  const float* esBrow = es2t + (size_t)hB * M;
  const unsigned short* SbtA0 = Sbt + (size_t)(hA * 32 + c16) * M;
  const unsigned short* SbtA1 = Sbt + (size_t)(hA * 32 + 16 + c16) * M;
  const unsigned short* SbtB0 = Sbt + (size_t)(hB * 32 + c16) * M;
  const unsigned short* SbtB1 = Sbt + (size_t)(hB * 32 + 16 + c16) * M;
  f32x4 accA0 = {0.f, 0.f, 0.f, 0.f}, accA1 = accA0, denA = accA0;
  f32x4 accB0 = accA0, accB1 = accA0, denB = accA0;
  union { bfrag v; int i[4]; } uo;
#pragma unroll
  for (int e = 0; e < 4; ++e) uo.i[e] = 0x3F803F80;   // bf16(1.0) pairs
  const bfrag ones = uo.v;

  // 64-m steps: all VMEM hoisted to the top, two compute groups below.
  for (int m0 = mstart; m0 < mend; m0 += 64) {
    const int wi = m0 >> 5;
    const unsigned w0 = adjrow[wi];
    const unsigned w1 = adjrow[wi + 1];
    const int moa = m0 + g * 8;
    const int mob = moa + 32;
    f4 eA0 = *(const f4*)(esArow + moa);
    f4 eA1 = *(const f4*)(esArow + moa + 4);
    f4 eB0 = *(const f4*)(esBrow + moa);
    f4 eB1 = *(const f4*)(esBrow + moa + 4);
    f4 fA0 = *(const f4*)(esArow + mob);
    f4 fA1 = *(const f4*)(esArow + mob + 4);
    f4 fB0 = *(const f4*)(esBrow + mob);
    f4 fB1 = *(const f4*)(esBrow + mob + 4);
    bfrag bA0a = *(const bfrag*)(SbtA0 + moa);
    bfrag bA1a = *(const bfrag*)(SbtA1 + moa);
    bfrag bB0a = *(const bfrag*)(SbtB0 + moa);
    bfrag bB1a = *(const bfrag*)(SbtB1 + moa);
    bfrag bA0b = *(const bfrag*)(SbtA0 + mob);
    bfrag bA1b = *(const bfrag*)(SbtA1 + mob);
    bfrag bB0b = *(const bfrag*)(SbtB0 + mob);
    bfrag bB1b = *(const bfrag*)(SbtB1 + mob);
    const unsigned bits0 = (w0 >> (g * 8)) & 0xffu;
    const unsigned bits1 = (w1 >> (g * 8)) & 0xffu;
    // sub-step 0
    bfrag aA = make_pfrag2(etA, eA0, eA1, bits0);
    bfrag aB = make_pfrag2(etB, eB0, eB1, bits0);
    accA0 = MFMA16(aA, bA0a, accA0);
    accA1 = MFMA16(aA, bA1a, accA1);
    denA  = MFMA16(aA, ones, denA);
    accB0 = MFMA16(aB, bB0a, accB0);
    accB1 = MFMA16(aB, bB1a, accB1);
    denB  = MFMA16(aB, ones, denB);
    // sub-step 1
    bfrag cA = make_pfrag2(etA, fA0, fA1, bits1);
    bfrag cB = make_pfrag2(etB, fB0, fB1, bits1);
    accA0 = MFMA16(cA, bA0b, accA0);
    accA1 = MFMA16(cA, bA1b, accA1);
    denA  = MFMA16(cA, ones, denA);
    accB0 = MFMA16(cB, bB0b, accB0);
    accB1 = MFMA16(cB, bB1b, accB1);
    denB  = MFMA16(cB, ones, denB);
  }

  // C/D layout: col = c16, row = g*4 + reg
#define EPILOGUE(acc0, acc1, den, h)                                          \
  {                                                                           \
    const int c0 = (h) * 32 + c16, c1 = (h) * 32 + 16 + c16;                  \
    if (FINAL) {                                                              \
      const float g0 = bng[c0] * BNF, b0 = bnb[c0];                           \
      const float g1 = bng[c1] * BNF, b1 = bnb[c1];                           \
      _Pragma("unroll") for (int i = 0; i < 4; ++i) {                         \
        float rs = 1.f / fmaxf(den[i], 1e-30f);                               \
        float* op = outp + (size_t)(n0 + g * 4 + i) * 256;                    \
        op[c0] = fmaxf(fmaf(acc0[i] * rs, g0, b0), 0.f);                      \
        op[c1] = fmaxf(fmaf(acc1[i] * rs, g1, b1), 0.f);                      \
      }                                                                       \
    } else {                                                                  \
      _Pragma("unroll") for (int i = 0; i < 4; ++i) {                         \
        size_t rr = (size_t)chunk * ROWS + n0 + g * 4 + i;                    \
        pnum[rr * 256 + c0] = acc0[i];                                        \
        pnum[rr * 256 + c1] = acc1[i];                                        \
        if (c16 == 0) pden[rr * 8 + (h)] = den[i];                            \
      }                                                                       \
    }                                                                         \
  }
  EPILOGUE(accA0, accA1, denA, hA)
  EPILOGUE(accB0, accB1, denB, hB)
#undef EPILOGUE
}

// ------- finalize: sum partials, divide, BN, ReLU (both sides) -------
__global__ __launch_bounds__(256) void finalize_k(
    const float* __restrict__ pnum_c, const float* __restrict__ pden_c,
    const float* __restrict__ pnum_d, const float* __restrict__ pden_d,
    float* __restrict__ out,
    const float* __restrict__ gc, const float* __restrict__ bc,
    const float* __restrict__ gd, const float* __restrict__ bd,
    int cc_c, int cc_d) {
  const int b = blockIdx.x;
  const bool cs = b < 1024;
  const int idx = (cs ? b : b - 1024) * 256 + threadIdx.x;
  const int rows = cs ? 4096 : 2048;
  const int cc = cs ? cc_c : cc_d;
  const float* pnum = cs ? pnum_c : pnum_d;
  const float* pden = cs ? pden_c : pden_d;
  const float* bng = cs ? gc : gd;
  const float* bnb = cs ? bc : bd;
  float* outp = cs ? out : out + (size_t)4096 * 256;
  int r = idx >> 6, c4 = (idx & 63) * 4;
  int h = c4 >> 5;
  f4 num = {0.f, 0.f, 0.f, 0.f};
  float den = 0.f;
  for (int c = 0; c < cc; ++c) {
    size_t rr = (size_t)c * rows + r;
    num += *(const f4*)(pnum + rr * 256 + c4);
    den += pden[rr * 8 + h];
  }
  float rs = 1.f / fmaxf(den, 1e-30f);
  f4 gm = *(const f4*)(bng + c4);
  f4 bb = *(const f4*)(bnb + c4);
  f4 o;
  o.x = fmaxf(fmaf(num.x * rs, gm.x * BNF, bb.x), 0.f);
  o.y = fmaxf(fmaf(num.y * rs, gm.y * BNF, bb.y), 0.f);
  o.z = fmaxf(fmaf(num.z * rs, gm.z * BNF, bb.z), 0.f);
  o.w = fmaxf(fmaf(num.w * rs, gm.w * BNF, bb.w), 0.f);
  *(f4*)(outp + (size_t)r * 256 + c4) = o;
}

extern "C" void kernel_launch(void* const* d_in, const int* in_sizes, int n_in,
                              void* d_out, int out_size, void* d_ws, size_t ws_size,
                              hipStream_t stream) {
  const float* c_feat = (const float*)d_in[0];   // [4096,256]
  const float* d_feat = (const float*)d_in[1];   // [2048,256]
  const int*   adj    = (const int*)d_in[2];     // [4096,2048]
  const float* c_W    = (const float*)d_in[3];
  const float* c_a    = (const float*)d_in[4];   // [8,64]
  const float* d_W    = (const float*)d_in[5];
  const float* d_a    = (const float*)d_in[6];
  const float* c_bn_g = (const float*)d_in[7];
  const float* c_bn_b = (const float*)d_in[8];
  const float* d_bn_g = (const float*)d_in[9];
  const float* d_bn_b = (const float*)d_in[10];
  float* out = (float*)d_out;

  char* w = (char*)d_ws;
  size_t off = 0;
  auto take = [&](size_t bytes) -> char* {
    char* p = w + off;
    off += (bytes + 255) & ~(size_t)255;
    return p;
  };
  unsigned short* Sbt_c = (unsigned short*)take(256 * 2048 * 2);
  unsigned short* Sbt_d = (unsigned short*)take(256 * 4096 * 2);
  float* et2_c  = (float*)take(4096 * 8 * 4);
  float* es2t_c = (float*)take(8 * 2048 * 4);
  float* et2_d  = (float*)take(2048 * 8 * 4);
  float* es2t_d = (float*)take(8 * 4096 * 4);
  float* wa_c   = (float*)take(8 * 256 * 4);
  float* wa_d   = (float*)take(8 * 256 * 4);
  unsigned* adjP  = (unsigned*)take(4096 * 64 * 4);
  unsigned* adjPT = (unsigned*)take(2048 * 128 * 4);

  // chunk-count ladder by available scratch
  const size_t base = off;
  const size_t PC = (size_t)4096 * 256 * 4, PD = (size_t)2048 * 256 * 4;
  const size_t DC = 4096 * 8 * 4, DD = 2048 * 8 * 4;
  auto need = [&](int a, int b2) -> size_t {
    return base + (size_t)a * (PC + DC) + (size_t)b2 * (PD + DD) + 4096;
  };
  int ccc = 0, ccd = 0;
  if (ws_size >= need(4, 8))      { ccc = 4; ccd = 8; }
  else if (ws_size >= need(4, 4)) { ccc = 4; ccd = 4; }
  else if (ws_size >= need(2, 4)) { ccc = 2; ccd = 4; }
  else if (ws_size >= need(2, 2)) { ccc = 2; ccd = 2; }

  float* pden_c = nullptr; float* pden_d = nullptr;
  float* pnum_c = nullptr; float* pnum_d = nullptr;
  if (ccc) {
    pden_c = (float*)take((size_t)ccc * DC);
    pden_d = (float*)take((size_t)ccd * DD);
    pnum_c = (float*)take((size_t)ccc * PC);
    pnum_d = (float*)take((size_t)ccd * PD);
  }

  dim3 blk(256);
  wa_both<<<16, blk, 0, stream>>>(c_W, c_a, d_W, d_a, wa_c, wa_d);
  pack_adj<<<dim3(32, 64), blk, 0, stream>>>(adj, adjP, adjPT);
  gemm_both<<<384, blk, 0, stream>>>(c_feat, d_feat, c_W, d_W, c_a, d_a,
                                     Sbt_c, Sbt_d, es2t_c, es2t_d);
  et_both<<<192, blk, 0, stream>>>(c_feat, wa_c, d_feat, wa_d, et2_c, et2_d);

  if (ccc) {
    fused_attn<0><<<256 * ccc + 128 * ccd, blk, 0, stream>>>(
        et2_c, es2t_c, adjP, Sbt_c, pnum_c, pden_c,
        et2_d, es2t_d, adjPT, Sbt_d, pnum_d, pden_d,
        nullptr, c_bn_g, c_bn_b, d_bn_g, d_bn_b,
        256 * ccc, 2048 / ccc, 4096 / ccd);
    finalize_k<<<1536, blk, 0, stream>>>(pnum_c, pden_c, pnum_d, pden_d, out,
                                         c_bn_g, c_bn_b, d_bn_g, d_bn_b, ccc, ccd);
  } else {
    fused_attn<1><<<384, blk, 0, stream>>>(
        et2_c, es2t_c, adjP, Sbt_c, nullptr, nullptr,
        et2_d, es2t_d, adjPT, Sbt_d, nullptr, nullptr,
        out, c_bn_g, c_bn_b, d_bn_g, d_bn_b, 256, 2048, 4096);
  }
}